// Round 7
// baseline (15704.950 us; speedup 1.0000x reference)
//
#include <hip/hip_runtime.h>

#define U_ 1024
#define B_ 64
#define T_ 256
#define DIN_ 128
#define BT_ (B_*T_)
#define G_ 1024   // 4 blocks/CU by launch_bounds(256,4)
#define NG 4      // 4 groups of 16 batch rows, pipelined
#define XVB 576   // blocks >= XVB pin their B2 xv stripe

// sync line layout (one line = 16 u32 = 64B)
#define FA_L    0     // 256: g*64+bi       A own-flags (=step+1)
#define RELA_L  256   // 256: g*64+i        tq release
#define CE_L    512   // 64 : b             per-b ew arrivals (16/step)
#define CZ_L    576   // 64 : g*16+i        zh arrivals (16/line/step)
#define CX_L    640   // 64 : g*16+i        B2 arrivals (16/line/step)
#define RELX_L  704   // 256: g*64+i        ctx+zh release
#define CC_L    960   // 64 : g*16+i        C arrivals (16/line/step)
#define RELC_L  1024  // 256: g*64+i        h release
#define SYNC_N  (1280*16)

typedef __attribute__((ext_vector_type(4))) float f32x4;
typedef __attribute__((ext_vector_type(8))) short s16x8;
typedef __attribute__((ext_vector_type(4))) unsigned short u16x4;
typedef unsigned long long u64;

union U64F2 { u64 q; float f[2]; };
union U64H4 { u64 q; unsigned short h[4]; };

__device__ inline unsigned short f2bf(float x){
  unsigned u = __float_as_uint(x);
  u += 0x7FFFu + ((u >> 16) & 1u);
  return (unsigned short)(u >> 16);
}
__device__ inline float bf2f(unsigned short b){ return __uint_as_float(((unsigned)b) << 16); }
__device__ inline float fast_rcp(float x){ return __builtin_amdgcn_rcpf(x); }
__device__ inline float fast_tanh(float x){
  float e = __expf(2.0f * x);
  return 1.0f - 2.0f * fast_rcp(e + 1.0f);
}
__device__ inline float fast_sig(float x){
  return fast_rcp(1.0f + __expf(-x));
}

__device__ inline u64 ald64(const u64* p){
  return __hip_atomic_load((u64*)p, __ATOMIC_RELAXED, __HIP_MEMORY_SCOPE_AGENT);
}
__device__ inline void ast64(u64* p, u64 v){
  __hip_atomic_store(p, v, __ATOMIC_RELAXED, __HIP_MEMORY_SCOPE_AGENT);
}
__device__ inline float aldf(const float* p){
  return __hip_atomic_load((float*)p, __ATOMIC_RELAXED, __HIP_MEMORY_SCOPE_AGENT);
}
__device__ inline void astf(float* p, float v){
  __hip_atomic_store(p, v, __ATOMIC_RELAXED, __HIP_MEMORY_SCOPE_AGENT);
}
__device__ inline unsigned ald32(const unsigned* p){
  return __hip_atomic_load((unsigned*)p, __ATOMIC_RELAXED, __HIP_MEMORY_SCOPE_AGENT);
}
__device__ inline void ast32(unsigned* p, unsigned v){
  __hip_atomic_store(p, v, __ATOMIC_RELAXED, __HIP_MEMORY_SCOPE_AGENT);
}
__device__ inline void aadd32(unsigned* p, unsigned v){
  __hip_atomic_fetch_add(p, v, __ATOMIC_RELAXED, __HIP_MEMORY_SCOPE_AGENT);
}
__device__ inline s16x8 frag_ald(const u64* p){
  u64 a = ald64(p), b = ald64(p + 1);
  union { u64 q[2]; s16x8 v; } x; x.q[0] = a; x.q[1] = b; return x.v;
}

__device__ inline void wait1(unsigned* line, unsigned tgt){
  if (threadIdx.x == 0){
    while (ald32(line) < tgt) __builtin_amdgcn_s_sleep(2);
  }
  __syncthreads();
}

// score over 16 u: V·tanh(q+k) via tanh-addition identity
__device__ inline float score8(s16x8 k0, s16x8 k1, const float* tqv, const float* Vv){
  float s = 0.f;
  #pragma unroll
  for (int e = 0; e < 8; ++e){
    float kf = bf2f((unsigned short)k0[e]);
    float num = tqv[e] + kf;
    float den = fmaf(tqv[e], kf, 1.0f);
    s += Vv[e] * num * fast_rcp(den);
  }
  #pragma unroll
  for (int e = 0; e < 8; ++e){
    float kf = bf2f((unsigned short)k1[e]);
    float num = tqv[8+e] + kf;
    float den = fmaf(tqv[8+e], kf, 1.0f);
    s += Vv[8+e] * num * fast_rcp(den);
  }
  return s;
}

// ---------------- init ----------------
__global__ void init_kernel(float* c, unsigned short* hb0, unsigned short* hb1,
                            unsigned* sync, const float* V, float* vbound){
  int i = blockIdx.x * 256 + threadIdx.x;
  if (i < B_*U_){ c[i] = 0.f; hb0[i] = 0; hb1[i] = 0; }
  if (i < SYNC_N) sync[i] = 0u;
  if (blockIdx.x == 0){
    __shared__ float red[4];
    int t = threadIdx.x, lane = t & 63, w = t >> 6;
    float s = fabsf(V[t]) + fabsf(V[t+256]) + fabsf(V[t+512]) + fabsf(V[t+768]);
    #pragma unroll
    for (int mk = 32; mk >= 1; mk >>= 1) s += __shfl_xor(s, mk, 64);
    if (lane == 0) red[w] = s;
    __syncthreads();
    if (t == 0) vbound[0] = red[0] + red[1] + red[2] + red[3];
  }
}

// ---------------- transpose + bf16 convert ----------------
__global__ void transpose_bf_kernel(const float* W, unsigned short* WT, int K, int N){
  int ktiles = K >> 5;
  int kb = blockIdx.x % ktiles, nb = blockIdx.x / ktiles;
  __shared__ float tile[32][33];
  int x = threadIdx.x & 31, y8 = threadIdx.x >> 5;
  #pragma unroll
  for (int i = 0; i < 4; ++i){
    int y = y8*4 + i;
    tile[y][x] = W[(size_t)(kb*32 + y)*N + nb*32 + x];
  }
  __syncthreads();
  #pragma unroll
  for (int i = 0; i < 4; ++i){
    int y = y8*4 + i;
    WT[(size_t)(nb*32 + y)*K + kb*32 + x] = f2bf(tile[x][y]);
  }
}

// ---------------- embedding GEMMs ----------------
template<int AF32>
__global__ __launch_bounds__(256) void gemm_embed(const void* Aptr, const unsigned short* BT,
                                                  const float* bias, unsigned short* Cout,
                                                  int K, int act){
  int nb = blockIdx.x & 15, mb = blockIdx.x >> 4;
  int lane = threadIdx.x & 63, w = threadIdx.x >> 6;
  int l15 = lane & 15, quad = lane >> 4;
  int m0 = mb*64 + w*16;
  int arow = m0 + l15;
  f32x4 acc[4];
  #pragma unroll
  for (int nt = 0; nt < 4; ++nt) acc[nt] = (f32x4){0.f,0.f,0.f,0.f};

  for (int k0 = 0; k0 < K; k0 += 32){
    int koff = k0 + quad*8;
    s16x8 a8;
    if (AF32){
      const float* ap = (const float*)Aptr + (size_t)arow*K + koff;
      f32x4 lo = *(const f32x4*)ap;
      f32x4 hi = *(const f32x4*)(ap + 4);
      a8[0]=(short)f2bf(lo[0]); a8[1]=(short)f2bf(lo[1]); a8[2]=(short)f2bf(lo[2]); a8[3]=(short)f2bf(lo[3]);
      a8[4]=(short)f2bf(hi[0]); a8[5]=(short)f2bf(hi[1]); a8[6]=(short)f2bf(hi[2]); a8[7]=(short)f2bf(hi[3]);
    } else {
      a8 = *(const s16x8*)((const unsigned short*)Aptr + (size_t)arow*K + koff);
    }
    #pragma unroll
    for (int nt = 0; nt < 4; ++nt){
      const unsigned short* bp = BT + (size_t)(nb*64 + nt*16 + l15)*K + koff;
      s16x8 b8 = *(const s16x8*)bp;
      acc[nt] = __builtin_amdgcn_mfma_f32_16x16x32_bf16(a8, b8, acc[nt], 0, 0, 0);
    }
  }
  #pragma unroll
  for (int nt = 0; nt < 4; ++nt){
    int col = nb*64 + nt*16 + l15;
    float bv = bias[col];
    #pragma unroll
    for (int r = 0; r < 4; ++r){
      int row = m0 + quad*4 + r;
      float v = acc[nt][r] + bv;
      v = (act == 0) ? fmaxf(v, 0.f) : fast_tanh(v);
      Cout[(size_t)row*U_ + col] = f2bf(v);
    }
  }
}

// ---------------- persistent sequential kernel ----------------
struct SeqP {
  const unsigned short *W1Tb, *WkTb, *WrTb, *tk, *xv;
  const float *b1, *bl, *V, *Wo, *bo, *vbound;
  float *tq, *ew, *c, *zh, *out_part, *out;
  unsigned short *ctxb, *hb0, *hb1;
  unsigned *sync;
};

// NG=4 batch-group pipelined schedule. Per-group gate chain identical in
// topology to the verified round-2 chain; groups stagger through the shared
// weight blocks. All WAR chains re-derived per group (see session notes):
// every step-s+1 writer of a group-g buffer is transitively gated behind the
// group-g readers of step s. out_part is parity-double-buffered with the
// reader placed in-group at step top (read ordered before next overwrite via
// the reader's own B2->cX->relX chain).
__global__ __launch_bounds__(256, 4) void seq_kernel(SeqP p){
  const int bi = blockIdx.x;
  const int t  = threadIdx.x;
  const int lane = t & 63, w = t >> 6;
  const int l15 = lane & 15, quad = lane >> 4;
  const int b_own = bi >> 4, tg_own = bi & 15, g_own = bi >> 8;
  __shared__ __align__(16) unsigned short lfrag[16384];
  __shared__ __align__(16) float smem[1664];
  unsigned* sync = p.sync;
  const float Mb = p.vbound[0];

  // ---- one-time LDS pinning ----
  if (bi < XVB){
    const unsigned short* wsrc;
    if (bi < 64)       wsrc = p.W1Tb + (size_t)(bi*16 + l15)*U_;
    else if (bi < 320) wsrc = p.WrTb + (size_t)((bi - 64)*16 + l15)*U_;
    else               wsrc = p.WkTb + (size_t)((l15 >> 2)*U_ + (bi - 320)*4 + (l15 & 3))*U_;
    for (int it = w; it < 32; it += 4)
      *(s16x8*)&lfrag[it*512 + lane*8] = *(const s16x8*)(wsrc + it*32 + quad*8);
  } else {
    const unsigned short* xsrc = p.xv + (size_t)b_own*T_*U_ + tg_own*64;
    #pragma unroll
    for (int it = 0; it < 8; ++it){
      int r = (t >> 3) + 32*it;
      *(s16x8*)&lfrag[r*64 + (t & 7)*8] = *(const s16x8*)(xsrc + (size_t)r*U_ + (t & 7)*8);
    }
  }
  __syncthreads();

  u64* tqu  = (u64*)p.tq;
  u64* ewu  = (u64*)p.ew;
  u64* ctxu = (u64*)p.ctxb;

  for (int step = 0; step < T_; ++step){
    const u64* hbRu = (const u64*)((step & 1) ? p.hb1 : p.hb0);
    u64*       hbWu = (u64*)((step & 1) ? p.hb0 : p.hb1);

    // ---------- phase lambdas ----------
    auto OUTD = [&](int sidx){
      float v = aldf(&p.out_part[(sidx & 1)*16384 + b_own*256 + t]);
      #pragma unroll
      for (int mk = 32; mk >= 1; mk >>= 1) v += __shfl_xor(v, mk, 64);
      if (lane == 0) smem[w] = v;
      __syncthreads();
      if (t == 0) p.out[sidx*64 + b_own] = smem[0] + smem[1] + smem[2] + smem[3] + p.bo[0];
      __syncthreads();
    };

    auto PH_A = [&](int g){
      wait1(&sync[(RELC_L + g*64 + (bi & 63))*16], (unsigned)step);
      f32x4 acc = (f32x4){0.f,0.f,0.f,0.f};
      #pragma unroll
      for (int i = 0; i < 8; ++i){
        int k = w*256 + i*32;
        s16x8 a8 = frag_ald(hbRu + (g*16 + l15)*256 + ((k + quad*8) >> 2));
        acc = __builtin_amdgcn_mfma_f32_16x16x32_bf16(a8, *(const s16x8*)&lfrag[(k >> 5)*512 + lane*8], acc, 0, 0, 0);
      }
      #pragma unroll
      for (int r = 0; r < 4; ++r) smem[w*256 + (quad*4 + r)*16 + l15] = acc[r];
      __syncthreads();
      {
        int m = t >> 4, col = t & 15;
        int jcol = bi*16 + col;
        float v = smem[t] + smem[256+t] + smem[512+t] + smem[768+t] + p.b1[jcol];
        astf(&p.tq[(size_t)(g*16 + m)*U_ + jcol], fast_tanh(v));
      }
      __syncthreads();
      if (t == 0) ast32(&sync[(FA_L + g*64 + bi)*16], (unsigned)(step + 1));
    };

    auto AGGA = [&](int g){
      if (t < 64){
        unsigned tgt = (unsigned)(step + 1);
        for (;;){
          bool ok = ald32(&sync[(FA_L + g*64 + t)*16]) >= tgt;
          if (__ballot(ok) == ~0ull) break;
          __builtin_amdgcn_s_sleep(1);
        }
        ast32(&sync[(RELA_L + g*64 + t)*16], tgt);
      }
    };

    auto PH_Z = [&](int g){
      wait1(&sync[(RELC_L + g*64 + (bi & 63))*16], (unsigned)step);
      f32x4 acc = (f32x4){0.f,0.f,0.f,0.f};
      #pragma unroll
      for (int i = 0; i < 8; ++i){
        int k = w*256 + i*32;
        s16x8 a8 = frag_ald(hbRu + (g*16 + l15)*256 + ((k + quad*8) >> 2));
        acc = __builtin_amdgcn_mfma_f32_16x16x32_bf16(a8, *(const s16x8*)&lfrag[(k >> 5)*512 + lane*8], acc, 0, 0, 0);
      }
      #pragma unroll
      for (int r = 0; r < 4; ++r) smem[w*256 + (quad*4 + r)*16 + l15] = acc[r];
      __syncthreads();
      {
        int m = t >> 4, col = t & 15;
        int jcol = (bi - 64)*16 + col;
        float v = smem[t] + smem[256+t] + smem[512+t] + smem[768+t] + p.bl[jcol];
        astf(&p.zh[jcol*64 + g*16 + m], v);
      }
      __syncthreads();
      if (t == 0) aadd32(&sync[(CZ_L + g*16 + ((bi - 64) & 15))*16], 1u);
    };

    auto B1 = [&](){
      int g = g_own;
      wait1(&sync[(RELA_L + g*64 + (bi & 63))*16], (unsigned)(step + 1));
      float tqv[16], Vv[16];
      int tqb = (b_own*U_ + lane*16) >> 1;
      #pragma unroll
      for (int i = 0; i < 8; ++i){
        U64F2 x; x.q = ald64(tqu + tqb + i);
        tqv[2*i] = x.f[0]; tqv[2*i+1] = x.f[1];
      }
      const float* Vp = p.V + lane*16;
      #pragma unroll
      for (int i = 0; i < 16; i += 4) *(f32x4*)&Vv[i] = *(const f32x4*)(Vp + i);
      int trow = tg_own*16 + w*4;
      float sr[4];
      const unsigned short* kp = p.tk + (size_t)(b_own*T_ + trow)*U_ + lane*16;
      #pragma unroll
      for (int rr = 0; rr < 4; ++rr){
        s16x8 k0 = *(const s16x8*)(kp + (size_t)rr*U_);
        s16x8 k1 = *(const s16x8*)(kp + (size_t)rr*U_ + 8);
        sr[rr] = score8(k0, k1, tqv, Vv);
      }
      #pragma unroll
      for (int mk = 32; mk >= 1; mk >>= 1){
        #pragma unroll
        for (int rr = 0; rr < 4; ++rr) sr[rr] += __shfl_xor(sr[rr], mk, 64);
      }
      if (lane == 0){
        int eb = (b_own*T_ + trow) >> 1;
        #pragma unroll
        for (int j = 0; j < 2; ++j){
          U64F2 x;
          x.f[0] = __expf(sr[2*j]   - Mb);
          x.f[1] = __expf(sr[2*j+1] - Mb);
          ast64(ewu + eb + j, x.q);
        }
      }
      __syncthreads();
      if (t == 0) aadd32(&sync[(CE_L + b_own)*16], 1u);
    };

    auto B2 = [&](){
      wait1(&sync[(CE_L + b_own)*16], 16u * (unsigned)(step + 1));
      float* ewL = smem;
      float* tmp = smem + 256;
      float* red = smem + 272;
      if (t < 128){
        U64F2 x; x.q = ald64(ewu + b_own*128 + t);
        ewL[2*t] = x.f[0]; ewL[2*t+1] = x.f[1];
      }
      __syncthreads();
      float e = ewL[t];
      float sum = e;
      #pragma unroll
      for (int mk = 32; mk >= 1; mk >>= 1) sum += __shfl_xor(sum, mk, 64);
      if (lane == 0) tmp[w] = sum;
      __syncthreads();
      float rd = fast_rcp(tmp[0] + tmp[1] + tmp[2] + tmp[3]);

      int ui = t & 15, tgp = t >> 4;
      f32x4 a = (f32x4){0.f,0.f,0.f,0.f};
      if (bi >= XVB){
        #pragma unroll 4
        for (int t8 = tgp; t8 < T_; t8 += 16){
          float wg = ewL[t8];
          u16x4 x4 = *(const u16x4*)&lfrag[t8*64 + ui*4];
          a[0] = fmaf(wg, bf2f(x4[0]), a[0]);
          a[1] = fmaf(wg, bf2f(x4[1]), a[1]);
          a[2] = fmaf(wg, bf2f(x4[2]), a[2]);
          a[3] = fmaf(wg, bf2f(x4[3]), a[3]);
        }
      } else {
        int u = tg_own*64 + ui*4;
        const unsigned short* xp = p.xv + (size_t)b_own*T_*U_ + u;
        #pragma unroll 4
        for (int t8 = tgp; t8 < T_; t8 += 16){
          float wg = ewL[t8];
          u16x4 x4 = *(const u16x4*)(xp + (size_t)t8*U_);
          a[0] = fmaf(wg, bf2f(x4[0]), a[0]);
          a[1] = fmaf(wg, bf2f(x4[1]), a[1]);
          a[2] = fmaf(wg, bf2f(x4[2]), a[2]);
          a[3] = fmaf(wg, bf2f(x4[3]), a[3]);
        }
      }
      *(f32x4*)&red[(tgp*16 + ui)*4] = a;
      __syncthreads();
      if (t < 16){
        f32x4 r = (f32x4){0.f,0.f,0.f,0.f};
        #pragma unroll
        for (int g2 = 0; g2 < 16; ++g2){
          f32x4 rr = *(f32x4*)&red[(g2*16 + t)*4];
          r[0]+=rr[0]; r[1]+=rr[1]; r[2]+=rr[2]; r[3]+=rr[3];
        }
        U64H4 cv;
        cv.h[0]=f2bf(r[0]*rd); cv.h[1]=f2bf(r[1]*rd); cv.h[2]=f2bf(r[2]*rd); cv.h[3]=f2bf(r[3]*rd);
        ast64(ctxu + b_own*256 + tg_own*16 + t, cv.q);
      }
      __syncthreads();
      if (t == 0) aadd32(&sync[(CX_L + g_own*16 + tg_own)*16], 1u);
    };

    auto AGGX = [&](int g){
      if (t < 64){
        unsigned tgt = 16u * (unsigned)(step + 1);
        for (;;){
          bool ok = (lane < 16) ? (ald32(&sync[(CX_L + g*16 + lane)*16]) >= tgt)
                  : (lane < 32) ? (ald32(&sync[(CZ_L + g*16 + (lane-16))*16]) >= tgt)
                  : true;
          if (__ballot(ok) == ~0ull) break;
          __builtin_amdgcn_s_sleep(1);
        }
        ast32(&sync[(RELX_L + g*64 + t)*16], (unsigned)(step + 1));
      }
    };

    auto PH_C = [&](int g){
      wait1(&sync[(RELX_L + g*64 + (bi & 63))*16], (unsigned)(step + 1));
      int cb = bi - 320, ub = cb*4;
      f32x4 acc = (f32x4){0.f,0.f,0.f,0.f};
      #pragma unroll
      for (int i = 0; i < 8; ++i){
        int k = w*256 + i*32;
        s16x8 a8 = frag_ald(ctxu + (g*16 + l15)*256 + ((k + quad*8) >> 2));
        acc = __builtin_amdgcn_mfma_f32_16x16x32_bf16(a8, *(const s16x8*)&lfrag[(k >> 5)*512 + lane*8], acc, 0, 0, 0);
      }
      #pragma unroll
      for (int r = 0; r < 4; ++r) smem[w*256 + (quad*4 + r)*16 + l15] = acc[r];
      __syncthreads();
      float* zs2 = smem + 1024;   // [col(16)][b-off(16)]
      float* hs  = smem + 1280;   // [ui(4)][b-off(16)]
      float* op  = smem + 1344;   // [ui(4)][b-off(16)]
      {
        int m = t >> 4, col = t & 15;
        int jcol = (col >> 2)*U_ + ub + (col & 3);
        float z = smem[t] + smem[256+t] + smem[512+t] + smem[768+t]
                + aldf(&p.zh[jcol*64 + g*16 + m]);
        zs2[col*16 + m] = z;
      }
      __syncthreads();
      if (t < 64){
        int boff = t & 15, ui = t >> 4;
        float zi = zs2[(0*4 + ui)*16 + boff];
        float zf = zs2[(1*4 + ui)*16 + boff];
        float zg = zs2[(2*4 + ui)*16 + boff];
        float zo = zs2[(3*4 + ui)*16 + boff];
        float ig = fast_sig(zi), fg = fast_sig(zf);
        float gg = fast_tanh(zg), og = fast_sig(zo);
        int u = ub + ui, bg = g*16 + boff;
        float cold = p.c[u*64 + bg];   // block-private across steps/groups
        float cn = fg*cold + ig*gg;
        float hn = og * fast_tanh(cn);
        p.c[u*64 + bg] = cn;
        hs[ui*16 + boff] = hn;
        op[ui*16 + boff] = hn * p.Wo[u];
      }
      __syncthreads();
      if (t < 16){
        int bg = g*16 + t;
        U64H4 h0;
        #pragma unroll
        for (int k = 0; k < 4; ++k) h0.h[k] = f2bf(hs[k*16 + t]);
        ast64(hbWu + bg*256 + cb, h0.q);
        float po = op[t] + op[16 + t] + op[32 + t] + op[48 + t];
        astf(&p.out_part[(step & 1)*16384 + bg*256 + cb], po);
      }
      __syncthreads();
      if (t == 0) aadd32(&sync[(CC_L + g*16 + (cb & 15))*16], 1u);
    };

    auto AGGC = [&](int g){
      if (t < 64){
        unsigned tgt = 16u * (unsigned)(step + 1);
        for (;;){
          bool ok = (lane < 16) ? (ald32(&sync[(CC_L + g*16 + lane)*16]) >= tgt) : true;
          if (__ballot(ok) == ~0ull) break;
          __builtin_amdgcn_s_sleep(1);
        }
        ast32(&sync[(RELC_L + g*64 + t)*16], (unsigned)(step + 1));
      }
    };

    // ---------- per-role sequence ----------
    // out-duty for b: block b*16+15 (in b's group) at step top — ordered
    // before its own B1/B2, so the next out_part overwrite (C_g[step+1],
    // gated via this block's B2->cX->relX chain) cannot race the read.
    if (tg_own == 15 && step > 0){
      wait1(&sync[(RELC_L + g_own*64 + (bi & 63))*16], (unsigned)step);
      OUTD(step - 1);
    }

    if (bi < 64){                      // A-blocks (b 0..3, g0)
      PH_A(0); if (bi == 0) AGGA(0);
      B1(); B2(); if (bi == 0) AGGX(0);
      PH_A(1); if (bi == 1) AGGA(1);
      PH_A(2); if (bi == 2) AGGA(2);
      PH_A(3); if (bi == 3) AGGA(3);
    } else if (bi < 256){              // Wr-blocks, own b in g0
      PH_Z(0);
      B1(); B2();
      PH_Z(1); PH_Z(2); PH_Z(3);
      if (bi == 65) AGGC(0);
    } else if (bi < 320){              // Wr-blocks, own b in g1
      PH_Z(0); PH_Z(1);
      B1(); B2(); if (bi == 256) AGGX(1);
      PH_Z(2); PH_Z(3);
      if (bi == 257) AGGC(1);
    } else if (bi < 512){              // C-blocks, own b in g1
      B1(); B2();
      PH_C(0); PH_C(1); PH_C(2); PH_C(3);
    } else if (bi < 576){              // C-blocks, own b in g2
      PH_C(0);
      B1(); B2();
      PH_C(1); PH_C(2); PH_C(3);
    } else if (bi < 768){              // xv-blocks, g2
      B1(); B2();
      if (bi == 576) AGGX(2);
      if (bi == 577) AGGC(2);
    } else {                           // xv-blocks, g3
      B1(); B2();
      if (bi == 768) AGGX(3);
      if (bi == 769) AGGC(3);
    }
  }

  // ---- final output row ----
  if (tg_own == 15){
    wait1(&sync[(RELC_L + g_own*64 + (bi & 63))*16], (unsigned)T_);
    float v = aldf(&p.out_part[((T_-1) & 1)*16384 + b_own*256 + t]);
    #pragma unroll
    for (int mk = 32; mk >= 1; mk >>= 1) v += __shfl_xor(v, mk, 64);
    if (lane == 0) smem[w] = v;
    __syncthreads();
    if (t == 0) p.out[(T_-1)*64 + b_own] = smem[0] + smem[1] + smem[2] + smem[3] + p.bo[0];
  }
}

extern "C" void kernel_launch(void* const* d_in, const int* in_sizes, int n_in,
                              void* d_out, int out_size, void* d_ws, size_t ws_size,
                              hipStream_t stream){
  const float* inputs = (const float*)d_in[0];
  const float* We1 = (const float*)d_in[1];
  const float* be1 = (const float*)d_in[2];
  const float* We2 = (const float*)d_in[3];
  const float* be2 = (const float*)d_in[4];
  const float* W1  = (const float*)d_in[5];
  const float* b1  = (const float*)d_in[6];
  const float* W2  = (const float*)d_in[7];
  const float* b2  = (const float*)d_in[8];
  const float* V   = (const float*)d_in[9];
  // d_in[10] = bV: softmax shift-invariant, dropped
  const float* Wk  = (const float*)d_in[11];
  const float* Wr  = (const float*)d_in[12];
  const float* bl  = (const float*)d_in[13];
  const float* Wo  = (const float*)d_in[14];
  const float* bo  = (const float*)d_in[15];
  float* out = (float*)d_out;

  char* ws = (char*)d_ws;
  size_t off = 0;
  auto alloc = [&](size_t bytes) -> void* {
    void* pp = ws + off;
    off = (off + bytes + 255) & ~(size_t)255;
    return pp;
  };
  unsigned short* We1Tb = (unsigned short*)alloc((size_t)1024*128*2);
  unsigned short* We2Tb = (unsigned short*)alloc((size_t)1024*1024*2);
  unsigned short* W2Tb  = (unsigned short*)alloc((size_t)1024*1024*2);
  unsigned short* W1Tb  = (unsigned short*)alloc((size_t)1024*1024*2);
  unsigned short* WkTb  = (unsigned short*)alloc((size_t)4096*1024*2);
  unsigned short* WrTb  = (unsigned short*)alloc((size_t)4096*1024*2);
  unsigned short* h1tk  = (unsigned short*)alloc((size_t)BT_*U_*2);  // h1, then tk
  unsigned short* xv    = (unsigned short*)alloc((size_t)BT_*U_*2);
  float*          c     = (float*)alloc((size_t)B_*U_*4);
  unsigned short* hb0   = (unsigned short*)alloc((size_t)B_*U_*2);
  unsigned short* hb1   = (unsigned short*)alloc((size_t)B_*U_*2);
  unsigned short* ctxb  = (unsigned short*)alloc((size_t)B_*U_*2);
  float*          tq    = (float*)alloc((size_t)B_*U_*4);
  float*          ew    = (float*)alloc((size_t)B_*T_*4);
  float*          zh    = (float*)alloc((size_t)4*U_*64*4);
  float*          out_part = (float*)alloc((size_t)2*64*256*4);
  unsigned*       sync  = (unsigned*)alloc((size_t)SYNC_N*4);
  float*          vbound= (float*)alloc(256);
  if (ws_size < off) return;  // workspace too small: fail loudly

  init_kernel<<<256, 256, 0, stream>>>(c, hb0, hb1, sync, V, vbound);
  transpose_bf_kernel<<<(128/32)*(1024/32),  256, 0, stream>>>(We1, We1Tb, 128, 1024);
  transpose_bf_kernel<<<(1024/32)*(1024/32), 256, 0, stream>>>(We2, We2Tb, 1024, 1024);
  transpose_bf_kernel<<<(1024/32)*(1024/32), 256, 0, stream>>>(W2,  W2Tb,  1024, 1024);
  transpose_bf_kernel<<<(1024/32)*(1024/32), 256, 0, stream>>>(W1,  W1Tb,  1024, 1024);
  transpose_bf_kernel<<<(1024/32)*(4096/32), 256, 0, stream>>>(Wk,  WkTb,  1024, 4096);
  transpose_bf_kernel<<<(1024/32)*(4096/32), 256, 0, stream>>>(Wr,  WrTb,  1024, 4096);

  gemm_embed<1><<<4096, 256, 0, stream>>>((const void*)inputs, We1Tb, be1, h1tk, DIN_, 0);
  gemm_embed<0><<<4096, 256, 0, stream>>>((const void*)h1tk,   We2Tb, be2, xv,   U_,   0);
  gemm_embed<0><<<4096, 256, 0, stream>>>((const void*)xv,     W2Tb,  b2,  h1tk, U_,   1);

  SeqP sp;
  sp.W1Tb = W1Tb; sp.WkTb = WkTb; sp.WrTb = WrTb; sp.tk = h1tk; sp.xv = xv;
  sp.b1 = b1; sp.bl = bl; sp.V = V; sp.Wo = Wo; sp.bo = bo; sp.vbound = vbound;
  sp.tq = tq; sp.ew = ew; sp.c = c; sp.zh = zh;
  sp.out_part = out_part; sp.out = out;
  sp.ctxb = ctxb; sp.hb0 = hb0; sp.hb1 = hb1; sp.sync = sync;
  seq_kernel<<<dim3(G_), dim3(256), 0, stream>>>(sp);
}

// Round 8
// 13270.468 us; speedup vs baseline: 1.1835x; 1.1835x over previous
//
#include <hip/hip_runtime.h>

#define U_ 1024
#define B_ 64
#define T_ 256
#define DIN_ 128
#define BT_ (B_*T_)
#define G_ 1024  // 4 blocks/CU by launch_bounds(256,4)
#define NWB 576  // 0..63 W1, 64..319 Wr, 320..575 Wk; 576..1023 pin their B2 xv stripe

// sync line layout (u32 units; one line = 16 u32 = 64B)
#define FA_L   0     // 64 lines: tq producer own-flags (=step+1)
#define RELA_L 64    // 64 lines: tq release (aggA = block 0)
#define CE_L   128   // 64 lines: per-b ew arrival counts (16 adds/step)
#define CZ_L   192   // 16 lines: zh arrival counts (16 adds/line/step)
#define CX_L   208   // 64 lines: B2-all arrival counts (16 adds/line/step)
#define CC_L   336   // 16 lines: C arrival counts (16 adds/line/step)
#define SYNC_N (416*16)

typedef __attribute__((ext_vector_type(4))) float f32x4;
typedef __attribute__((ext_vector_type(8))) short s16x8;
typedef __attribute__((ext_vector_type(4))) unsigned short u16x4;
typedef unsigned long long u64;

union U64F2 { u64 q; float f[2]; };
union U64H4 { u64 q; unsigned short h[4]; };

__device__ inline unsigned short f2bf(float x){
  unsigned u = __float_as_uint(x);
  u += 0x7FFFu + ((u >> 16) & 1u);
  return (unsigned short)(u >> 16);
}
__device__ inline float bf2f(unsigned short b){ return __uint_as_float(((unsigned)b) << 16); }
__device__ inline float fast_rcp(float x){ return __builtin_amdgcn_rcpf(x); }
__device__ inline float fast_tanh(float x){
  float e = __expf(2.0f * x);
  return 1.0f - 2.0f * fast_rcp(e + 1.0f);
}
__device__ inline float fast_sig(float x){
  return fast_rcp(1.0f + __expf(-x));
}

// sc1 (agent-coherent, L3-point) accessors — no fences anywhere.
__device__ inline u64 ald64(const u64* p){
  return __hip_atomic_load((u64*)p, __ATOMIC_RELAXED, __HIP_MEMORY_SCOPE_AGENT);
}
__device__ inline void ast64(u64* p, u64 v){
  __hip_atomic_store(p, v, __ATOMIC_RELAXED, __HIP_MEMORY_SCOPE_AGENT);
}
__device__ inline float aldf(const float* p){
  return __hip_atomic_load((float*)p, __ATOMIC_RELAXED, __HIP_MEMORY_SCOPE_AGENT);
}
__device__ inline void astf(float* p, float v){
  __hip_atomic_store(p, v, __ATOMIC_RELAXED, __HIP_MEMORY_SCOPE_AGENT);
}
__device__ inline unsigned ald32(const unsigned* p){
  return __hip_atomic_load((unsigned*)p, __ATOMIC_RELAXED, __HIP_MEMORY_SCOPE_AGENT);
}
__device__ inline void ast32(unsigned* p, unsigned v){
  __hip_atomic_store(p, v, __ATOMIC_RELAXED, __HIP_MEMORY_SCOPE_AGENT);
}
__device__ inline void aadd32(unsigned* p, unsigned v){
  __hip_atomic_fetch_add(p, v, __ATOMIC_RELAXED, __HIP_MEMORY_SCOPE_AGENT);
}
__device__ inline s16x8 frag_ald(const u64* p){
  u64 a = ald64(p), b = ald64(p + 1);
  union { u64 q[2]; s16x8 v; } x; x.q[0] = a; x.q[1] = b; return x.v;
}

// thread0 polls one line >= tgt, then block barrier
__device__ inline void wait1(unsigned* line, unsigned tgt){
  if (threadIdx.x == 0){
    while (ald32(line) < tgt) __builtin_amdgcn_s_sleep(2);
  }
  __syncthreads();
}

// wave-0 polls the 16 cC lines >= tgt (direct, no aggregator hop)
__device__ inline void waitCC(unsigned* sync, unsigned tgt, int lane, int w){
  if (w == 0){
    for (;;){
      bool ok = (lane < 16) ? (ald32(&sync[(CC_L + lane)*16]) >= tgt) : true;
      if (__ballot(ok) == ~0ull) break;
      __builtin_amdgcn_s_sleep(1);
    }
  }
  __syncthreads();
}

// waves 0/1 poll the 64 cX + 16 cZ lines >= tgt (direct, no aggregator hop)
__device__ inline void waitXZ(unsigned* sync, unsigned tgt, int lane, int w){
  if (w == 0){
    for (;;){
      bool ok = ald32(&sync[(CX_L + lane)*16]) >= tgt;
      if (__ballot(ok) == ~0ull) break;
      __builtin_amdgcn_s_sleep(1);
    }
  } else if (w == 1){
    for (;;){
      bool ok = (lane < 16) ? (ald32(&sync[(CZ_L + lane)*16]) >= tgt) : true;
      if (__ballot(ok) == ~0ull) break;
      __builtin_amdgcn_s_sleep(1);
    }
  }
  __syncthreads();
}

// score over 16 u-elements: V·tanh(q+k) via tanh-addition identity
__device__ inline float score8(s16x8 k0, s16x8 k1, const float* tqv, const float* Vv){
  float s = 0.f;
  #pragma unroll
  for (int e = 0; e < 8; ++e){
    float kf = bf2f((unsigned short)k0[e]);
    float num = tqv[e] + kf;
    float den = fmaf(tqv[e], kf, 1.0f);
    s += Vv[e] * num * fast_rcp(den);
  }
  #pragma unroll
  for (int e = 0; e < 8; ++e){
    float kf = bf2f((unsigned short)k1[e]);
    float num = tqv[8+e] + kf;
    float den = fmaf(tqv[8+e], kf, 1.0f);
    s += Vv[8+e] * num * fast_rcp(den);
  }
  return s;
}

// ---------------- init ----------------
__global__ void init_kernel(float* c, unsigned short* hb0, unsigned short* hb1,
                            unsigned* sync, const float* V, float* vbound){
  int i = blockIdx.x * 256 + threadIdx.x;
  if (i < B_*U_){ c[i] = 0.f; hb0[i] = 0; hb1[i] = 0; }
  if (i < SYNC_N) sync[i] = 0u;
  if (blockIdx.x == 0){
    __shared__ float red[4];
    int t = threadIdx.x, lane = t & 63, w = t >> 6;
    float s = fabsf(V[t]) + fabsf(V[t+256]) + fabsf(V[t+512]) + fabsf(V[t+768]);
    #pragma unroll
    for (int mk = 32; mk >= 1; mk >>= 1) s += __shfl_xor(s, mk, 64);
    if (lane == 0) red[w] = s;
    __syncthreads();
    if (t == 0) vbound[0] = red[0] + red[1] + red[2] + red[3];
  }
}

// ---------------- transpose + bf16 convert: W[K][N] -> WT[N][K] ----------------
__global__ void transpose_bf_kernel(const float* W, unsigned short* WT, int K, int N){
  int ktiles = K >> 5;
  int kb = blockIdx.x % ktiles, nb = blockIdx.x / ktiles;
  __shared__ float tile[32][33];
  int x = threadIdx.x & 31, y8 = threadIdx.x >> 5;
  #pragma unroll
  for (int i = 0; i < 4; ++i){
    int y = y8*4 + i;
    tile[y][x] = W[(size_t)(kb*32 + y)*N + nb*32 + x];
  }
  __syncthreads();
  #pragma unroll
  for (int i = 0; i < 4; ++i){
    int y = y8*4 + i;
    WT[(size_t)(nb*32 + y)*K + kb*32 + x] = f2bf(tile[x][y]);
  }
}

// ---------------- embedding GEMMs (once per launch) ----------------
template<int AF32>
__global__ __launch_bounds__(256) void gemm_embed(const void* Aptr, const unsigned short* BT,
                                                  const float* bias, unsigned short* Cout,
                                                  int K, int act){
  int nb = blockIdx.x & 15, mb = blockIdx.x >> 4;
  int lane = threadIdx.x & 63, w = threadIdx.x >> 6;
  int l15 = lane & 15, quad = lane >> 4;
  int m0 = mb*64 + w*16;
  int arow = m0 + l15;
  f32x4 acc[4];
  #pragma unroll
  for (int nt = 0; nt < 4; ++nt) acc[nt] = (f32x4){0.f,0.f,0.f,0.f};

  for (int k0 = 0; k0 < K; k0 += 32){
    int koff = k0 + quad*8;
    s16x8 a8;
    if (AF32){
      const float* ap = (const float*)Aptr + (size_t)arow*K + koff;
      f32x4 lo = *(const f32x4*)ap;
      f32x4 hi = *(const f32x4*)(ap + 4);
      a8[0]=(short)f2bf(lo[0]); a8[1]=(short)f2bf(lo[1]); a8[2]=(short)f2bf(lo[2]); a8[3]=(short)f2bf(lo[3]);
      a8[4]=(short)f2bf(hi[0]); a8[5]=(short)f2bf(hi[1]); a8[6]=(short)f2bf(hi[2]); a8[7]=(short)f2bf(hi[3]);
    } else {
      a8 = *(const s16x8*)((const unsigned short*)Aptr + (size_t)arow*K + koff);
    }
    #pragma unroll
    for (int nt = 0; nt < 4; ++nt){
      const unsigned short* bp = BT + (size_t)(nb*64 + nt*16 + l15)*K + koff;
      s16x8 b8 = *(const s16x8*)bp;
      acc[nt] = __builtin_amdgcn_mfma_f32_16x16x32_bf16(a8, b8, acc[nt], 0, 0, 0);
    }
  }
  #pragma unroll
  for (int nt = 0; nt < 4; ++nt){
    int col = nb*64 + nt*16 + l15;
    float bv = bias[col];
    #pragma unroll
    for (int r = 0; r < 4; ++r){
      int row = m0 + quad*4 + r;
      float v = acc[nt][r] + bv;
      v = (act == 0) ? fmaxf(v, 0.f) : fast_tanh(v);
      Cout[(size_t)row*U_ + col] = f2bf(v);
    }
  }
}

// ---------------- persistent sequential kernel ----------------
struct SeqP {
  const unsigned short *W1Tb, *WkTb, *WrTb, *tk, *xv;
  const float *b1, *bl, *V, *Wo, *bo, *vbound;
  float *tq, *ew, *c, *zh, *out_part, *out;
  unsigned short *ctxb, *hb0, *hb1;
  unsigned *sync;
};

__device__ inline void out_reduce(const SeqP& p, int b, int sidx, float* smem,
                                  int t, int lane, int w){
  float v = aldf(&p.out_part[b*256 + t]);
  #pragma unroll
  for (int mk = 32; mk >= 1; mk >>= 1) v += __shfl_xor(v, mk, 64);
  if (lane == 0) smem[w] = v;
  __syncthreads();
  if (t == 0) p.out[sidx*64 + b] = smem[0] + smem[1] + smem[2] + smem[3] + p.bo[0];
  __syncthreads();
}

// Round-6 verified schedule (flag-gated, xv stripes pinned for bi>=NWB) with
// TWO aggregator hops removed: relC and relX are gone; their consumers poll
// the underlying arrival counters (cC 16 lines; cX 64 + cZ 16 lines)
// directly. Gating CONDITIONS are identical to round 6 — only the transport
// changed — so all WAR/deadlock arguments carry over. relA keeps its
// aggregator (1024 consumers x 64 lines would be 65K pollers).
__global__ __launch_bounds__(256, 4) void seq_kernel(SeqP p){
  const int bi = blockIdx.x;
  const int t  = threadIdx.x;
  const int lane = t & 63, w = t >> 6;
  const int l15 = lane & 15, quad = lane >> 4;
  __shared__ __align__(16) unsigned short lfrag[16384];
  __shared__ __align__(16) float smem[1664];
  unsigned* sync = p.sync;
  const float Mb = p.vbound[0];   // softmax shift bound: |score| < sum|V|

  // ---- one-time LDS pinning ----
  if (bi < NWB){
    const unsigned short* wsrc;
    if (bi < 64)       wsrc = p.W1Tb + (size_t)(bi*16 + l15)*U_;
    else if (bi < 320) wsrc = p.WrTb + (size_t)((bi - 64)*16 + l15)*U_;
    else               wsrc = p.WkTb + (size_t)((l15 >> 2)*U_ + (bi - 320)*4 + (l15 & 3))*U_;
    for (int it = w; it < 32; it += 4)
      *(s16x8*)&lfrag[it*512 + lane*8] = *(const s16x8*)(wsrc + it*32 + quad*8);
  } else {
    // pin the B2 xv stripe: lfrag[t8*64 + uu] = xv[b][t8][ug*64 + uu]
    const unsigned short* xsrc = p.xv + (size_t)(bi >> 4)*T_*U_ + (bi & 15)*64;
    #pragma unroll
    for (int it = 0; it < 8; ++it){
      int r = (t >> 3) + 32*it;
      *(s16x8*)&lfrag[r*64 + (t & 7)*8] = *(const s16x8*)(xsrc + (size_t)r*U_ + (t & 7)*8);
    }
  }
  __syncthreads();

  u64* tqu  = (u64*)p.tq;
  u64* ewu  = (u64*)p.ew;
  u64* zhu  = (u64*)p.zh;
  u64* ctxu = (u64*)p.ctxb;

  for (int step = 0; step < T_; ++step){
    const u64* hbRu = (const u64*)((step & 1) ? p.hb1 : p.hb0);
    u64*       hbWu = (u64*)((step & 1) ? p.hb0 : p.hb1);

    // ===== step-top gates + Phase A =====
    if (bi < 64){
      waitCC(sync, 16u * (unsigned)step, lane, w);   // h_{t-1} ready (direct poll)
      int jcol = bi*16 + l15;
      int rbase = (w*16 + l15) << 8;           // row * 256 u64
      f32x4 acc = (f32x4){0.f,0.f,0.f,0.f};
      #pragma unroll 8
      for (int k = 0; k < U_; k += 32){
        s16x8 a8 = frag_ald(hbRu + rbase + ((k + quad*8) >> 2));
        s16x8 b8 = *(const s16x8*)&lfrag[(k >> 5)*512 + lane*8];   // W1 (LDS)
        acc = __builtin_amdgcn_mfma_f32_16x16x32_bf16(a8, b8, acc, 0, 0, 0);
      }
      float bj = p.b1[jcol];
      float* tqs = smem;   // 16*68
      #pragma unroll
      for (int r = 0; r < 4; ++r)
        tqs[l15*68 + w*16 + quad*4 + r] = fast_tanh(acc[r] + bj);
      __syncthreads();
      if (t < 64){
        int ub64 = (t*U_ + bi*16) >> 1;        // float-pair index
        #pragma unroll
        for (int cc = 0; cc < 16; cc += 2){
          U64F2 x;
          x.f[0] = tqs[(cc+0)*68 + t];
          x.f[1] = tqs[(cc+1)*68 + t];
          ast64(tqu + ub64 + (cc >> 1), x.q);
        }
      }
      __syncthreads();                          // drain tq stores
      if (t == 0) ast32(&sync[(FA_L + bi)*16], (unsigned)(step + 1));
      if (bi == 0){                             // aggA: gather 64 flags, release
        if (t < 64){
          unsigned tgt = (unsigned)(step + 1);
          for (;;){
            bool ok = ald32(&sync[(FA_L + t)*16]) >= tgt;
            if (__ballot(ok) == ~0ull) break;
            __builtin_amdgcn_s_sleep(1);
          }
          ast32(&sync[(RELA_L + t)*16], tgt);
        }
      }
    } else if (bi < 320){
      waitCC(sync, 16u * (unsigned)step, lane, w);   // h_{t-1} ready (direct poll)
      int bz = bi - 64;
      int rbase = (w*16 + l15) << 8;
      int jc0 = bz*16 + l15;
      f32x4 acc0 = (f32x4){0.f,0.f,0.f,0.f};
      #pragma unroll 8
      for (int k = 0; k < U_; k += 32){
        s16x8 a8 = frag_ald(hbRu + rbase + ((k + quad*8) >> 2));
        s16x8 b8 = *(const s16x8*)&lfrag[(k >> 5)*512 + lane*8];   // Wr (LDS)
        acc0 = __builtin_amdgcn_mfma_f32_16x16x32_bf16(a8, b8, acc0, 0, 0, 0);
      }
      float bl0 = p.bl[jc0];
      int brow = w*16 + quad*4;
      U64F2 x;
      int i0 = (jc0*64 + brow) >> 1;
      x.f[0] = acc0[0] + bl0; x.f[1] = acc0[1] + bl0; ast64(zhu + i0, x.q);
      x.f[0] = acc0[2] + bl0; x.f[1] = acc0[3] + bl0; ast64(zhu + i0 + 1, x.q);
      __syncthreads();                          // drain zh stores
      if (t == 0) aadd32(&sync[(CZ_L + ((bi - 64) & 15))*16], 1u);
    } else if (bi >= 960){
      waitCC(sync, 16u * (unsigned)step, lane, w);   // h/out_part ready (direct poll)
      if (step > 0) out_reduce(p, bi - 960, step - 1, smem, t, lane, w);
    }
    // blocks 320..959: no step-top work

    // ===== gate: tq ready -> Phase B1 (all blocks, 16 t-rows each) =====
    wait1(&sync[(RELA_L + (bi & 63))*16], (unsigned)(step + 1));
    {
      int b = bi >> 4, tg = bi & 15;
      float tqv[16], Vv[16];
      int tqb = (b*U_ + lane*16) >> 1;
      #pragma unroll
      for (int i = 0; i < 8; ++i){
        U64F2 x; x.q = ald64(tqu + tqb + i);
        tqv[2*i] = x.f[0]; tqv[2*i+1] = x.f[1];
      }
      const float* Vp = p.V + lane*16;
      #pragma unroll
      for (int i = 0; i < 16; i += 4) *(f32x4*)&Vv[i] = *(const f32x4*)(Vp + i);
      int trow = tg*16 + w*4;
      float sr[4];
      // all blocks stream tk (plain loads; read-once per step)
      const unsigned short* kp = p.tk + (size_t)(b*T_ + trow)*U_ + lane*16;
      #pragma unroll
      for (int rr = 0; rr < 4; ++rr){
        s16x8 k0 = *(const s16x8*)(kp + (size_t)rr*U_);
        s16x8 k1 = *(const s16x8*)(kp + (size_t)rr*U_ + 8);
        sr[rr] = score8(k0, k1, tqv, Vv);
      }
      #pragma unroll
      for (int mk = 32; mk >= 1; mk >>= 1){
        #pragma unroll
        for (int rr = 0; rr < 4; ++rr) sr[rr] += __shfl_xor(sr[rr], mk, 64);
      }
      if (lane == 0){
        int eb = (b*T_ + trow) >> 1;
        #pragma unroll
        for (int j = 0; j < 2; ++j){
          U64F2 x;
          x.f[0] = __expf(sr[2*j]   - Mb);
          x.f[1] = __expf(sr[2*j+1] - Mb);
          ast64(ewu + eb + j, x.q);
        }
      }
    }
    __syncthreads();                            // drain ew stores
    if (t == 0) aadd32(&sync[(CE_L + (bi >> 4))*16], 1u);

    // ===== gate: all same-b ew rows ready -> Phase B2 =====
    wait1(&sync[(CE_L + (bi >> 4))*16], 16u * (unsigned)(step + 1));
    {
      int b = bi >> 4, ug = bi & 15;
      float* ewL = smem;        // 256
      float* tmp = smem + 256;  // 16
      float* red = smem + 272;  // 16*16*4 = 1024
      if (t < 128){
        U64F2 x; x.q = ald64(ewu + b*128 + t);
        ewL[2*t] = x.f[0]; ewL[2*t+1] = x.f[1];
      }
      __syncthreads();
      float e = ewL[t];
      float sum = e;
      #pragma unroll
      for (int mk = 32; mk >= 1; mk >>= 1) sum += __shfl_xor(sum, mk, 64);
      if (lane == 0) tmp[w] = sum;
      __syncthreads();
      float rd = fast_rcp(tmp[0] + tmp[1] + tmp[2] + tmp[3]);

      int ui = t & 15, tgp = t >> 4;
      f32x4 a = (f32x4){0.f,0.f,0.f,0.f};
      if (bi >= NWB){
        // xv stripe is LDS-pinned: zero global traffic in B2
        #pragma unroll 4
        for (int t8 = tgp; t8 < T_; t8 += 16){
          float wg = ewL[t8];
          u16x4 x4 = *(const u16x4*)&lfrag[t8*64 + ui*4];
          a[0] = fmaf(wg, bf2f(x4[0]), a[0]);
          a[1] = fmaf(wg, bf2f(x4[1]), a[1]);
          a[2] = fmaf(wg, bf2f(x4[2]), a[2]);
          a[3] = fmaf(wg, bf2f(x4[3]), a[3]);
        }
      } else {
        int u = ug*64 + ui*4;
        const unsigned short* xp = p.xv + (size_t)b*T_*U_ + u;
        #pragma unroll 4
        for (int t8 = tgp; t8 < T_; t8 += 16){
          float wg = ewL[t8];
          u16x4 x4 = *(const u16x4*)(xp + (size_t)t8*U_);
          a[0] = fmaf(wg, bf2f(x4[0]), a[0]);
          a[1] = fmaf(wg, bf2f(x4[1]), a[1]);
          a[2] = fmaf(wg, bf2f(x4[2]), a[2]);
          a[3] = fmaf(wg, bf2f(x4[3]), a[3]);
        }
      }
      *(f32x4*)&red[(tgp*16 + ui)*4] = a;
      __syncthreads();
      if (t < 16){
        f32x4 r = (f32x4){0.f,0.f,0.f,0.f};
        #pragma unroll
        for (int g = 0; g < 16; ++g){
          f32x4 rr = *(f32x4*)&red[(g*16 + t)*4];
          r[0]+=rr[0]; r[1]+=rr[1]; r[2]+=rr[2]; r[3]+=rr[3];
        }
        U64H4 cv;
        cv.h[0]=f2bf(r[0]*rd); cv.h[1]=f2bf(r[1]*rd); cv.h[2]=f2bf(r[2]*rd); cv.h[3]=f2bf(r[3]*rd);
        ast64(ctxu + b*256 + ug*16 + t, cv.q);
      }
    }
    __syncthreads();                            // drain ctx stores
    if (t == 0) aadd32(&sync[(CX_L + (bi & 63))*16], 1u);

    // ===== gate: ctx+zh ready -> Phase C (blocks 320..575, 4 u's each) =====
    if (bi >= 320 && bi < NWB){
      waitXZ(sync, 16u * (unsigned)(step + 1), lane, w);   // direct poll, no aggX
      int cb = bi - 320;
      int ub = cb*4;
      int gate = l15 >> 2, uo = l15 & 3;
      int jcol = gate*U_ + ub + uo;
      int rbase = (w*16 + l15) << 8;
      f32x4 acc = (f32x4){0.f,0.f,0.f,0.f};
      #pragma unroll 8
      for (int k = 0; k < U_; k += 32){
        s16x8 a8 = frag_ald(ctxu + rbase + ((k + quad*8) >> 2));
        acc = __builtin_amdgcn_mfma_f32_16x16x32_bf16(a8, *(const s16x8*)&lfrag[(k >> 5)*512 + lane*8], acc, 0, 0, 0);
      }
      int brow = w*16 + quad*4;
      int zi0 = (jcol*64 + brow) >> 1;
      U64F2 z0, z1;
      z0.q = ald64(zhu + zi0); z1.q = ald64(zhu + zi0 + 1);
      acc[0] += z0.f[0]; acc[1] += z0.f[1]; acc[2] += z1.f[0]; acc[3] += z1.f[1];
      float* zs = smem;          // 16*68 = 1088
      float* hs = smem + 1088;   // 256
      float* op = smem + 1344;   // 256
      *(f32x4*)&zs[l15*68 + brow] = acc;
      __syncthreads();
      {
        int b = t & 63, ui = t >> 6;   // ui in 0..3
        int u = ub + ui;
        float zi = zs[(0*4 + ui)*68 + b];
        float zf = zs[(1*4 + ui)*68 + b];
        float zg = zs[(2*4 + ui)*68 + b];
        float zo = zs[(3*4 + ui)*68 + b];
        float ig = fast_sig(zi), fg = fast_sig(zf);
        float gg = fast_tanh(zg), og = fast_sig(zo);
        float cold = p.c[u*64 + b];    // block-private across steps
        float cn = fg*cold + ig*gg;
        float hn = og * fast_tanh(cn);
        p.c[u*64 + b] = cn;
        hs[ui*64 + b] = hn;
        op[ui*64 + b] = hn * p.Wo[u];
      }
      __syncthreads();
      if (t < 64){
        U64H4 h0;
        #pragma unroll
        for (int k = 0; k < 4; ++k) h0.h[k] = f2bf(hs[k*64 + t]);
        ast64(hbWu + t*256 + cb, h0.q);
        float po = op[t] + op[64 + t] + op[128 + t] + op[192 + t];
        astf(&p.out_part[t*256 + cb], po);
      }
      __syncthreads();                          // drain h/out_part stores
      if (t == 0) aadd32(&sync[(CC_L + ((bi - 320) & 15))*16], 1u);
    }
  }

  // ===== final out reduction =====
  if (bi >= 960){
    waitCC(sync, 16u * (unsigned)T_, lane, w);
    out_reduce(p, bi - 960, T_ - 1, smem, t, lane, w);
  }
}

extern "C" void kernel_launch(void* const* d_in, const int* in_sizes, int n_in,
                              void* d_out, int out_size, void* d_ws, size_t ws_size,
                              hipStream_t stream){
  const float* inputs = (const float*)d_in[0];
  const float* We1 = (const float*)d_in[1];
  const float* be1 = (const float*)d_in[2];
  const float* We2 = (const float*)d_in[3];
  const float* be2 = (const float*)d_in[4];
  const float* W1  = (const float*)d_in[5];
  const float* b1  = (const float*)d_in[6];
  const float* W2  = (const float*)d_in[7];
  const float* b2  = (const float*)d_in[8];
  const float* V   = (const float*)d_in[9];
  // d_in[10] = bV: softmax shift-invariant, dropped
  const float* Wk  = (const float*)d_in[11];
  const float* Wr  = (const float*)d_in[12];
  const float* bl  = (const float*)d_in[13];
  const float* Wo  = (const float*)d_in[14];
  const float* bo  = (const float*)d_in[15];
  float* out = (float*)d_out;

  char* ws = (char*)d_ws;
  size_t off = 0;
  auto alloc = [&](size_t bytes) -> void* {
    void* pp = ws + off;
    off = (off + bytes + 255) & ~(size_t)255;
    return pp;
  };
  unsigned short* We1Tb = (unsigned short*)alloc((size_t)1024*128*2);
  unsigned short* We2Tb = (unsigned short*)alloc((size_t)1024*1024*2);
  unsigned short* W2Tb  = (unsigned short*)alloc((size_t)1024*1024*2);
  unsigned short* W1Tb  = (unsigned short*)alloc((size_t)1024*1024*2);
  unsigned short* WkTb  = (unsigned short*)alloc((size_t)4096*1024*2);
  unsigned short* WrTb  = (unsigned short*)alloc((size_t)4096*1024*2);
  unsigned short* h1tk  = (unsigned short*)alloc((size_t)BT_*U_*2);  // h1, then tk
  unsigned short* xv    = (unsigned short*)alloc((size_t)BT_*U_*2);
  float*          c     = (float*)alloc((size_t)B_*U_*4);
  unsigned short* hb0   = (unsigned short*)alloc((size_t)B_*U_*2);
  unsigned short* hb1   = (unsigned short*)alloc((size_t)B_*U_*2);
  unsigned short* ctxb  = (unsigned short*)alloc((size_t)B_*U_*2);
  float*          tq    = (float*)alloc((size_t)B_*U_*4);
  float*          ew    = (float*)alloc((size_t)B_*T_*4);
  float*          zh    = (float*)alloc((size_t)4*U_*64*4);
  float*          out_part = (float*)alloc((size_t)64*256*4);
  unsigned*       sync  = (unsigned*)alloc((size_t)SYNC_N*4);
  float*          vbound= (float*)alloc(256);
  if (ws_size < off) return;  // workspace too small: fail loudly

  init_kernel<<<256, 256, 0, stream>>>(c, hb0, hb1, sync, V, vbound);
  transpose_bf_kernel<<<(128/32)*(1024/32),  256, 0, stream>>>(We1, We1Tb, 128, 1024);
  transpose_bf_kernel<<<(1024/32)*(1024/32), 256, 0, stream>>>(We2, We2Tb, 1024, 1024);
  transpose_bf_kernel<<<(1024/32)*(1024/32), 256, 0, stream>>>(W2,  W2Tb,  1024, 1024);
  transpose_bf_kernel<<<(1024/32)*(1024/32), 256, 0, stream>>>(W1,  W1Tb,  1024, 1024);
  transpose_bf_kernel<<<(1024/32)*(4096/32), 256, 0, stream>>>(Wk,  WkTb,  1024, 4096);
  transpose_bf_kernel<<<(1024/32)*(4096/32), 256, 0, stream>>>(Wr,  WrTb,  1024, 4096);

  gemm_embed<1><<<4096, 256, 0, stream>>>((const void*)inputs, We1Tb, be1, h1tk, DIN_, 0);
  gemm_embed<0><<<4096, 256, 0, stream>>>((const void*)h1tk,   We2Tb, be2, xv,   U_,   0);
  gemm_embed<0><<<4096, 256, 0, stream>>>((const void*)xv,     W2Tb,  b2,  h1tk, U_,   1);

  SeqP sp;
  sp.W1Tb = W1Tb; sp.WkTb = WkTb; sp.WrTb = WrTb; sp.tk = h1tk; sp.xv = xv;
  sp.b1 = b1; sp.bl = bl; sp.V = V; sp.Wo = Wo; sp.bo = bo; sp.vbound = vbound;
  sp.tq = tq; sp.ew = ew; sp.c = c; sp.zh = zh;
  sp.out_part = out_part; sp.out = out;
  sp.ctxb = ctxb; sp.hb0 = hb0; sp.hb1 = hb1; sp.sync = sync;
  seq_kernel<<<dim3(G_), dim3(256), 0, stream>>>(sp);
}

// Round 10
// 11338.541 us; speedup vs baseline: 1.3851x; 1.1704x over previous
//
#include <hip/hip_runtime.h>

#define U_ 1024
#define B_ 64
#define T_ 256
#define DIN_ 128
#define BT_ (B_*T_)
#define G_ 1024  // 4 blocks/CU by launch_bounds(256,4)
#define NWB 576  // 0..63 W1, 64..319 Wr, 320..575 Wk; 576..1023 pin their B2 xv stripe

// sync line layout (u32 units; one line = 16 u32 = 64B)
#define FA_L   0     // 64 lines: tq producer own-flags (=step+1)
#define RELA_L 64    // 64 lines: tq release (aggA = block 0)
#define CE_L   128   // 64 lines: per-b ew arrival counts (16 adds/step)
#define CZ_L   192   // 16 lines: zh arrival counts (16 adds/line/step)
#define CX_L   208   // 64 lines: B2-all arrival counts (16 adds/line/step)
#define RELX_L 272   // 64 lines: B2+zh release (aggX = block 576)
#define CC_L   336   // 16 lines: C arrival counts (16 adds/line/step)
#define RELC_L 352   // 64 lines: C release (aggC = block 960)
#define SYNC_N (416*16)

typedef __attribute__((ext_vector_type(4))) float f32x4;
typedef __attribute__((ext_vector_type(8))) short s16x8;
typedef __attribute__((ext_vector_type(4))) unsigned short u16x4;
typedef unsigned long long u64;

union U64F2 { u64 q; float f[2]; };
union U64H4 { u64 q; unsigned short h[4]; };

__device__ inline unsigned short f2bf(float x){
  unsigned u = __float_as_uint(x);
  u += 0x7FFFu + ((u >> 16) & 1u);
  return (unsigned short)(u >> 16);
}
__device__ inline float bf2f(unsigned short b){ return __uint_as_float(((unsigned)b) << 16); }
__device__ inline float fast_rcp(float x){ return __builtin_amdgcn_rcpf(x); }
__device__ inline float fast_tanh(float x){
  float e = __expf(2.0f * x);
  return 1.0f - 2.0f * fast_rcp(e + 1.0f);
}
__device__ inline float fast_sig(float x){
  return fast_rcp(1.0f + __expf(-x));
}

// sc1 (agent-coherent, L3-point) accessors.
__device__ inline u64 ald64(const u64* p){
  return __hip_atomic_load((u64*)p, __ATOMIC_RELAXED, __HIP_MEMORY_SCOPE_AGENT);
}
__device__ inline void ast64(u64* p, u64 v){
  __hip_atomic_store(p, v, __ATOMIC_RELAXED, __HIP_MEMORY_SCOPE_AGENT);
}
__device__ inline float aldf(const float* p){
  return __hip_atomic_load((float*)p, __ATOMIC_RELAXED, __HIP_MEMORY_SCOPE_AGENT);
}
__device__ inline void astf(float* p, float v){
  __hip_atomic_store(p, v, __ATOMIC_RELAXED, __HIP_MEMORY_SCOPE_AGENT);
}
__device__ inline unsigned ald32(const unsigned* p){
  return __hip_atomic_load((unsigned*)p, __ATOMIC_RELAXED, __HIP_MEMORY_SCOPE_AGENT);
}
__device__ inline void ast32(unsigned* p, unsigned v){
  __hip_atomic_store(p, v, __ATOMIC_RELAXED, __HIP_MEMORY_SCOPE_AGENT);
}
__device__ inline void aadd32(unsigned* p, unsigned v){
  __hip_atomic_fetch_add(p, v, __ATOMIC_RELAXED, __HIP_MEMORY_SCOPE_AGENT);
}
__device__ inline s16x8 frag_ald(const u64* p){
  u64 a = ald64(p), b = ald64(p + 1);
  union { u64 q[2]; s16x8 v; } x; x.q[0] = a; x.q[1] = b; return x.v;
}
__device__ inline s16x8 bc16(f32x4 v){ return __builtin_bit_cast(s16x8, v); }

// thread0 polls one line >= tgt, then block barrier
__device__ inline void wait1(unsigned* line, unsigned tgt){
  if (threadIdx.x == 0){
    while (ald32(line) < tgt) __builtin_amdgcn_s_sleep(2);
  }
  __syncthreads();
}

// poll + agent-acquire fence (L1/L2 invalidate): subsequent sc0/plain loads
// must not see stale per-XCD L2 data. Used only at gates whose consumers read
// broadcast buffers (h, ctx) via sc0 L2-allocating loads.
__device__ inline void wait1_acq(unsigned* line, unsigned tgt){
  if (threadIdx.x == 0){
    while (ald32(line) < tgt) __builtin_amdgcn_s_sleep(2);
    __builtin_amdgcn_fence(__ATOMIC_ACQUIRE, "agent");
  }
  __syncthreads();
}

// Batched sc0 row-GEMM: 4 batches x 8 in-flight global_load_dwordx4 (sc0 =
// L1-bypass, L2-ALLOCATE) -> vmcnt(0) -> sched_barrier -> 8 MFMAs against the
// LDS-pinned weight fragments. gp = per-lane global base (row*2048 + quad*16).
// sc0 lets ~40 co-XCD blocks share one L2 copy of the broadcast operand
// instead of each reading L3 (sc1 bypasses L2 entirely).
__device__ inline f32x4 bcast_gemm_sc0(const char* gp, const unsigned short* lfrag,
                                       int lane){
  f32x4 acc = (f32x4){0.f,0.f,0.f,0.f};
  #pragma unroll
  for (int ii = 0; ii < 4; ++ii){
    const char* g = gp + ii*512;
    f32x4 t0,t1,t2,t3,t4,t5,t6,t7;
    asm volatile("global_load_dwordx4 %0, %1, off sc0"            : "=v"(t0) : "v"(g));
    asm volatile("global_load_dwordx4 %0, %1, off offset:64 sc0"  : "=v"(t1) : "v"(g));
    asm volatile("global_load_dwordx4 %0, %1, off offset:128 sc0" : "=v"(t2) : "v"(g));
    asm volatile("global_load_dwordx4 %0, %1, off offset:192 sc0" : "=v"(t3) : "v"(g));
    asm volatile("global_load_dwordx4 %0, %1, off offset:256 sc0" : "=v"(t4) : "v"(g));
    asm volatile("global_load_dwordx4 %0, %1, off offset:320 sc0" : "=v"(t5) : "v"(g));
    asm volatile("global_load_dwordx4 %0, %1, off offset:384 sc0" : "=v"(t6) : "v"(g));
    asm volatile("global_load_dwordx4 %0, %1, off offset:448 sc0" : "=v"(t7) : "v"(g));
    asm volatile("s_waitcnt vmcnt(0)" ::: "memory");
    __builtin_amdgcn_sched_barrier(0);
    const unsigned short* lb = lfrag + (size_t)ii*8*512 + lane*8;
    acc = __builtin_amdgcn_mfma_f32_16x16x32_bf16(bc16(t0), *(const s16x8*)(lb + 0*512), acc, 0, 0, 0);
    acc = __builtin_amdgcn_mfma_f32_16x16x32_bf16(bc16(t1), *(const s16x8*)(lb + 1*512), acc, 0, 0, 0);
    acc = __builtin_amdgcn_mfma_f32_16x16x32_bf16(bc16(t2), *(const s16x8*)(lb + 2*512), acc, 0, 0, 0);
    acc = __builtin_amdgcn_mfma_f32_16x16x32_bf16(bc16(t3), *(const s16x8*)(lb + 3*512), acc, 0, 0, 0);
    acc = __builtin_amdgcn_mfma_f32_16x16x32_bf16(bc16(t4), *(const s16x8*)(lb + 4*512), acc, 0, 0, 0);
    acc = __builtin_amdgcn_mfma_f32_16x16x32_bf16(bc16(t5), *(const s16x8*)(lb + 5*512), acc, 0, 0, 0);
    acc = __builtin_amdgcn_mfma_f32_16x16x32_bf16(bc16(t6), *(const s16x8*)(lb + 6*512), acc, 0, 0, 0);
    acc = __builtin_amdgcn_mfma_f32_16x16x32_bf16(bc16(t7), *(const s16x8*)(lb + 7*512), acc, 0, 0, 0);
  }
  return acc;
}

// score over 16 u-elements: V·tanh(q+k) via tanh-addition identity
__device__ inline float score8(s16x8 k0, s16x8 k1, const float* tqv, const float* Vv){
  float s = 0.f;
  #pragma unroll
  for (int e = 0; e < 8; ++e){
    float kf = bf2f((unsigned short)k0[e]);
    float num = tqv[e] + kf;
    float den = fmaf(tqv[e], kf, 1.0f);
    s += Vv[e] * num * fast_rcp(den);
  }
  #pragma unroll
  for (int e = 0; e < 8; ++e){
    float kf = bf2f((unsigned short)k1[e]);
    float num = tqv[8+e] + kf;
    float den = fmaf(tqv[8+e], kf, 1.0f);
    s += Vv[8+e] * num * fast_rcp(den);
  }
  return s;
}

// ---------------- init ----------------
__global__ void init_kernel(float* c, unsigned short* hb0, unsigned short* hb1,
                            unsigned* sync, const float* V, float* vbound){
  int i = blockIdx.x * 256 + threadIdx.x;
  if (i < B_*U_){ c[i] = 0.f; hb0[i] = 0; hb1[i] = 0; }
  if (i < SYNC_N) sync[i] = 0u;
  if (blockIdx.x == 0){
    __shared__ float red[4];
    int t = threadIdx.x, lane = t & 63, w = t >> 6;
    float s = fabsf(V[t]) + fabsf(V[t+256]) + fabsf(V[t+512]) + fabsf(V[t+768]);
    #pragma unroll
    for (int mk = 32; mk >= 1; mk >>= 1) s += __shfl_xor(s, mk, 64);
    if (lane == 0) red[w] = s;
    __syncthreads();
    if (t == 0) vbound[0] = red[0] + red[1] + red[2] + red[3];
  }
}

// ---------------- transpose + bf16 convert: W[K][N] -> WT[N][K] ----------------
__global__ void transpose_bf_kernel(const float* W, unsigned short* WT, int K, int N){
  int ktiles = K >> 5;
  int kb = blockIdx.x % ktiles, nb = blockIdx.x / ktiles;
  __shared__ float tile[32][33];
  int x = threadIdx.x & 31, y8 = threadIdx.x >> 5;
  #pragma unroll
  for (int i = 0; i < 4; ++i){
    int y = y8*4 + i;
    tile[y][x] = W[(size_t)(kb*32 + y)*N + nb*32 + x];
  }
  __syncthreads();
  #pragma unroll
  for (int i = 0; i < 4; ++i){
    int y = y8*4 + i;
    WT[(size_t)(nb*32 + y)*K + kb*32 + x] = f2bf(tile[x][y]);
  }
}

// ---------------- embedding GEMMs (once per launch) ----------------
template<int AF32>
__global__ __launch_bounds__(256) void gemm_embed(const void* Aptr, const unsigned short* BT,
                                                  const float* bias, unsigned short* Cout,
                                                  int K, int act){
  int nb = blockIdx.x & 15, mb = blockIdx.x >> 4;
  int lane = threadIdx.x & 63, w = threadIdx.x >> 6;
  int l15 = lane & 15, quad = lane >> 4;
  int m0 = mb*64 + w*16;
  int arow = m0 + l15;
  f32x4 acc[4];
  #pragma unroll
  for (int nt = 0; nt < 4; ++nt) acc[nt] = (f32x4){0.f,0.f,0.f,0.f};

  for (int k0 = 0; k0 < K; k0 += 32){
    int koff = k0 + quad*8;
    s16x8 a8;
    if (AF32){
      const float* ap = (const float*)Aptr + (size_t)arow*K + koff;
      f32x4 lo = *(const f32x4*)ap;
      f32x4 hi = *(const f32x4*)(ap + 4);
      a8[0]=(short)f2bf(lo[0]); a8[1]=(short)f2bf(lo[1]); a8[2]=(short)f2bf(lo[2]); a8[3]=(short)f2bf(lo[3]);
      a8[4]=(short)f2bf(hi[0]); a8[5]=(short)f2bf(hi[1]); a8[6]=(short)f2bf(hi[2]); a8[7]=(short)f2bf(hi[3]);
    } else {
      a8 = *(const s16x8*)((const unsigned short*)Aptr + (size_t)arow*K + koff);
    }
    #pragma unroll
    for (int nt = 0; nt < 4; ++nt){
      const unsigned short* bp = BT + (size_t)(nb*64 + nt*16 + l15)*K + koff;
      s16x8 b8 = *(const s16x8*)bp;
      acc[nt] = __builtin_amdgcn_mfma_f32_16x16x32_bf16(a8, b8, acc[nt], 0, 0, 0);
    }
  }
  #pragma unroll
  for (int nt = 0; nt < 4; ++nt){
    int col = nb*64 + nt*16 + l15;
    float bv = bias[col];
    #pragma unroll
    for (int r = 0; r < 4; ++r){
      int row = m0 + quad*4 + r;
      float v = acc[nt][r] + bv;
      v = (act == 0) ? fmaxf(v, 0.f) : fast_tanh(v);
      Cout[(size_t)row*U_ + col] = f2bf(v);
    }
  }
}

// ---------------- persistent sequential kernel ----------------
struct SeqP {
  const unsigned short *W1Tb, *WkTb, *WrTb, *tk, *xv;
  const float *b1, *bl, *V, *Wo, *bo, *vbound;
  float *tq, *ew, *c, *zh, *out_part, *out;
  unsigned short *ctxb, *hb0, *hb1;
  unsigned *sync;
};

__device__ inline void out_reduce(const SeqP& p, int b, int sidx, float* smem,
                                  int t, int lane, int w){
  float v = aldf(&p.out_part[b*256 + t]);
  #pragma unroll
  for (int mk = 32; mk >= 1; mk >>= 1) v += __shfl_xor(v, mk, 64);
  if (lane == 0) smem[w] = v;
  __syncthreads();
  if (t == 0) astf(&p.out[sidx*64 + b], smem[0] + smem[1] + smem[2] + smem[3] + p.bo[0]);
  __syncthreads();
}

// Round-6 verified schedule (best: 11.4 ms clean). Transport-only change:
// the h (A/Z) and ctx (C) broadcast reads use sc0 L2-ALLOCATING batched-asm
// loads, with an agent-acquire fence (L2 invalidate) at the consuming gate to
// kill cross-step L2 staleness. Producers stay sc1 (data at L3 before flag).
// All dirty plain-stored state made inv-immune: c and out now sc1.
__global__ __launch_bounds__(256, 4) void seq_kernel(SeqP p){
  const int bi = blockIdx.x;
  const int t  = threadIdx.x;
  const int lane = t & 63, w = t >> 6;
  const int l15 = lane & 15, quad = lane >> 4;
  __shared__ __align__(16) unsigned short lfrag[16384];
  __shared__ __align__(16) float smem[1664];
  unsigned* sync = p.sync;
  const float Mb = p.vbound[0];   // softmax shift bound: |score| < sum|V|

  // ---- one-time LDS pinning ----
  if (bi < NWB){
    const unsigned short* wsrc;
    if (bi < 64)       wsrc = p.W1Tb + (size_t)(bi*16 + l15)*U_;
    else if (bi < 320) wsrc = p.WrTb + (size_t)((bi - 64)*16 + l15)*U_;
    else               wsrc = p.WkTb + (size_t)((l15 >> 2)*U_ + (bi - 320)*4 + (l15 & 3))*U_;
    for (int it = w; it < 32; it += 4)
      *(s16x8*)&lfrag[it*512 + lane*8] = *(const s16x8*)(wsrc + it*32 + quad*8);
  } else {
    // pin the B2 xv stripe: lfrag[t8*64 + uu] = xv[b][t8][ug*64 + uu]
    const unsigned short* xsrc = p.xv + (size_t)(bi >> 4)*T_*U_ + (bi & 15)*64;
    #pragma unroll
    for (int it = 0; it < 8; ++it){
      int r = (t >> 3) + 32*it;
      *(s16x8*)&lfrag[r*64 + (t & 7)*8] = *(const s16x8*)(xsrc + (size_t)r*U_ + (t & 7)*8);
    }
  }
  __syncthreads();

  u64* tqu  = (u64*)p.tq;
  u64* ewu  = (u64*)p.ew;
  u64* zhu  = (u64*)p.zh;
  u64* ctxu = (u64*)p.ctxb;

  for (int step = 0; step < T_; ++step){
    const u64* hbRu = (const u64*)((step & 1) ? p.hb1 : p.hb0);
    u64*       hbWu = (u64*)((step & 1) ? p.hb0 : p.hb1);

    // ===== step-top gates + Phase A =====
    if (bi < 64){
      wait1_acq(&sync[(RELC_L + (bi & 63))*16], (unsigned)step);   // h ready + L2 inv
      int jcol = bi*16 + l15;
      const char* hp = (const char*)hbRu + (size_t)(w*16 + l15)*2048 + quad*16;
      f32x4 acc = bcast_gemm_sc0(hp, lfrag, lane);   // W1 (LDS) x h (sc0/L2)
      float bj = p.b1[jcol];
      float* tqs = smem;   // 16*68
      #pragma unroll
      for (int r = 0; r < 4; ++r)
        tqs[l15*68 + w*16 + quad*4 + r] = fast_tanh(acc[r] + bj);
      __syncthreads();
      if (t < 64){
        int ub64 = (t*U_ + bi*16) >> 1;        // float-pair index
        #pragma unroll
        for (int cc = 0; cc < 16; cc += 2){
          U64F2 x;
          x.f[0] = tqs[(cc+0)*68 + t];
          x.f[1] = tqs[(cc+1)*68 + t];
          ast64(tqu + ub64 + (cc >> 1), x.q);
        }
      }
      __syncthreads();                          // drain tq stores
      if (t == 0) ast32(&sync[(FA_L + bi)*16], (unsigned)(step + 1));
      if (bi == 0){                             // aggA: gather 64 flags, release
        if (t < 64){
          unsigned tgt = (unsigned)(step + 1);
          for (;;){
            bool ok = ald32(&sync[(FA_L + t)*16]) >= tgt;
            if (__ballot(ok) == ~0ull) break;
            __builtin_amdgcn_s_sleep(1);
          }
          ast32(&sync[(RELA_L + t)*16], tgt);
        }
      }
    } else if (bi < 320){
      wait1_acq(&sync[(RELC_L + (bi & 63))*16], (unsigned)step);   // h ready + L2 inv
      int bz = bi - 64;
      int jc0 = bz*16 + l15;
      const char* hp = (const char*)hbRu + (size_t)(w*16 + l15)*2048 + quad*16;
      f32x4 acc0 = bcast_gemm_sc0(hp, lfrag, lane);  // Wr (LDS) x h (sc0/L2)
      float bl0 = p.bl[jc0];
      int brow = w*16 + quad*4;
      U64F2 x;
      int i0 = (jc0*64 + brow) >> 1;
      x.f[0] = acc0[0] + bl0; x.f[1] = acc0[1] + bl0; ast64(zhu + i0, x.q);
      x.f[0] = acc0[2] + bl0; x.f[1] = acc0[3] + bl0; ast64(zhu + i0 + 1, x.q);
      __syncthreads();                          // drain zh stores
      if (t == 0) aadd32(&sync[(CZ_L + ((bi - 64) & 15))*16], 1u);
    } else if (bi >= 960){
      if (bi == 960){                           // aggC: gather cC, release relC
        if (step > 0){
          if (t < 64){
            unsigned tgt = 16u * (unsigned)step;
            for (;;){
              bool ok = (t < 16) ? (ald32(&sync[(CC_L + t)*16]) >= tgt) : true;
              if (__ballot(ok) == ~0ull) break;
              __builtin_amdgcn_s_sleep(1);
            }
            ast32(&sync[(RELC_L + t)*16], (unsigned)step);
          }
          __syncthreads();
          out_reduce(p, 0, step - 1, smem, t, lane, w);
        }
      } else {
        wait1(&sync[(RELC_L + (bi & 63))*16], (unsigned)step);
        if (step > 0) out_reduce(p, bi - 960, step - 1, smem, t, lane, w);
      }
    }
    // blocks 320..959: no step-top work

    // ===== gate: tq ready -> Phase B1 (all blocks, 16 t-rows each) =====
    wait1(&sync[(RELA_L + (bi & 63))*16], (unsigned)(step + 1));
    {
      int b = bi >> 4, tg = bi & 15;
      float tqv[16], Vv[16];
      int tqb = (b*U_ + lane*16) >> 1;
      #pragma unroll
      for (int i = 0; i < 8; ++i){
        U64F2 x; x.q = ald64(tqu + tqb + i);
        tqv[2*i] = x.f[0]; tqv[2*i+1] = x.f[1];
      }
      const float* Vp = p.V + lane*16;
      #pragma unroll
      for (int i = 0; i < 16; i += 4) *(f32x4*)&Vv[i] = *(const f32x4*)(Vp + i);
      int trow = tg*16 + w*4;
      float sr[4];
      // all blocks stream tk (plain loads; read-once per step)
      const unsigned short* kp = p.tk + (size_t)(b*T_ + trow)*U_ + lane*16;
      #pragma unroll
      for (int rr = 0; rr < 4; ++rr){
        s16x8 k0 = *(const s16x8*)(kp + (size_t)rr*U_);
        s16x8 k1 = *(const s16x8*)(kp + (size_t)rr*U_ + 8);
        sr[rr] = score8(k0, k1, tqv, Vv);
      }
      #pragma unroll
      for (int mk = 32; mk >= 1; mk >>= 1){
        #pragma unroll
        for (int rr = 0; rr < 4; ++rr) sr[rr] += __shfl_xor(sr[rr], mk, 64);
      }
      if (lane == 0){
        int eb = (b*T_ + trow) >> 1;
        #pragma unroll
        for (int j = 0; j < 2; ++j){
          U64F2 x;
          x.f[0] = __expf(sr[2*j]   - Mb);
          x.f[1] = __expf(sr[2*j+1] - Mb);
          ast64(ewu + eb + j, x.q);
        }
      }
    }
    __syncthreads();                            // drain ew stores
    if (t == 0) aadd32(&sync[(CE_L + (bi >> 4))*16], 1u);

    // ===== gate: all same-b ew rows ready -> Phase B2 =====
    wait1(&sync[(CE_L + (bi >> 4))*16], 16u * (unsigned)(step + 1));
    {
      int b = bi >> 4, ug = bi & 15;
      float* ewL = smem;        // 256
      float* tmp = smem + 256;  // 16
      float* red = smem + 272;  // 16*16*4 = 1024
      if (t < 128){
        U64F2 x; x.q = ald64(ewu + b*128 + t);
        ewL[2*t] = x.f[0]; ewL[2*t+1] = x.f[1];
      }
      __syncthreads();
      float e = ewL[t];
      float sum = e;
      #pragma unroll
      for (int mk = 32; mk >= 1; mk >>= 1) sum += __shfl_xor(sum, mk, 64);
      if (lane == 0) tmp[w] = sum;
      __syncthreads();
      float rd = fast_rcp(tmp[0] + tmp[1] + tmp[2] + tmp[3]);

      int ui = t & 15, tgp = t >> 4;
      f32x4 a = (f32x4){0.f,0.f,0.f,0.f};
      if (bi >= NWB){
        // xv stripe is LDS-pinned: zero global traffic in B2
        #pragma unroll 4
        for (int t8 = tgp; t8 < T_; t8 += 16){
          float wg = ewL[t8];
          u16x4 x4 = *(const u16x4*)&lfrag[t8*64 + ui*4];
          a[0] = fmaf(wg, bf2f(x4[0]), a[0]);
          a[1] = fmaf(wg, bf2f(x4[1]), a[1]);
          a[2] = fmaf(wg, bf2f(x4[2]), a[2]);
          a[3] = fmaf(wg, bf2f(x4[3]), a[3]);
        }
      } else {
        int u = ug*64 + ui*4;
        const unsigned short* xp = p.xv + (size_t)b*T_*U_ + u;
        #pragma unroll 4
        for (int t8 = tgp; t8 < T_; t8 += 16){
          float wg = ewL[t8];
          u16x4 x4 = *(const u16x4*)(xp + (size_t)t8*U_);
          a[0] = fmaf(wg, bf2f(x4[0]), a[0]);
          a[1] = fmaf(wg, bf2f(x4[1]), a[1]);
          a[2] = fmaf(wg, bf2f(x4[2]), a[2]);
          a[3] = fmaf(wg, bf2f(x4[3]), a[3]);
        }
      }
      *(f32x4*)&red[(tgp*16 + ui)*4] = a;
      __syncthreads();
      if (t < 16){
        f32x4 r = (f32x4){0.f,0.f,0.f,0.f};
        #pragma unroll
        for (int g = 0; g < 16; ++g){
          f32x4 rr = *(f32x4*)&red[(g*16 + t)*4];
          r[0]+=rr[0]; r[1]+=rr[1]; r[2]+=rr[2]; r[3]+=rr[3];
        }
        U64H4 cv;
        cv.h[0]=f2bf(r[0]*rd); cv.h[1]=f2bf(r[1]*rd); cv.h[2]=f2bf(r[2]*rd); cv.h[3]=f2bf(r[3]*rd);
        ast64(ctxu + b*256 + ug*16 + t, cv.q);
      }
    }
    __syncthreads();                            // drain ctx stores
    if (t == 0) aadd32(&sync[(CX_L + (bi & 63))*16], 1u);

    if (bi == 576){                             // aggX: gather cX + cZ, release relX
      unsigned tgt = 16u * (unsigned)(step + 1);
      if (w == 0){
        for (;;){
          bool ok = ald32(&sync[(CX_L + lane)*16]) >= tgt;
          if (__ballot(ok) == ~0ull) break;
          __builtin_amdgcn_s_sleep(1);
        }
      } else if (w == 1){
        for (;;){
          bool ok = (lane < 16) ? (ald32(&sync[(CZ_L + lane)*16]) >= tgt) : true;
          if (__ballot(ok) == ~0ull) break;
          __builtin_amdgcn_s_sleep(1);
        }
      }
      __syncthreads();
      if (t < 64) ast32(&sync[(RELX_L + t)*16], (unsigned)(step + 1));
    }

    // ===== gate: ctx+zh ready -> Phase C (blocks 320..575, 4 u's each) =====
    if (bi >= 320 && bi < NWB){
      wait1_acq(&sync[(RELX_L + (bi & 63))*16], (unsigned)(step + 1));  // + L2 inv
      int cb = bi - 320;
      int ub = cb*4;
      int gate = l15 >> 2, uo = l15 & 3;
      int jcol = gate*U_ + ub + uo;
      const char* cp = (const char*)ctxu + (size_t)(w*16 + l15)*2048 + quad*16;
      f32x4 acc = bcast_gemm_sc0(cp, lfrag, lane);   // Wk (LDS) x ctx (sc0/L2)
      int brow = w*16 + quad*4;
      int zi0 = (jcol*64 + brow) >> 1;
      U64F2 z0, z1;
      z0.q = ald64(zhu + zi0); z1.q = ald64(zhu + zi0 + 1);
      acc[0] += z0.f[0]; acc[1] += z0.f[1]; acc[2] += z1.f[0]; acc[3] += z1.f[1];
      float* zs = smem;          // 16*68 = 1088
      float* hs = smem + 1088;   // 256
      float* op = smem + 1344;   // 256
      *(f32x4*)&zs[l15*68 + brow] = acc;
      __syncthreads();
      {
        int b = t & 63, ui = t >> 6;   // ui in 0..3
        int u = ub + ui;
        float zi = zs[(0*4 + ui)*68 + b];
        float zf = zs[(1*4 + ui)*68 + b];
        float zg = zs[(2*4 + ui)*68 + b];
        float zo = zs[(3*4 + ui)*68 + b];
        float ig = fast_sig(zi), fg = fast_sig(zf);
        float gg = fast_tanh(zg), og = fast_sig(zo);
        float cold = aldf(&p.c[u*64 + b]);   // sc1: immune to neighbor L2-inv
        float cn = fg*cold + ig*gg;
        float hn = og * fast_tanh(cn);
        astf(&p.c[u*64 + b], cn);
        hs[ui*64 + b] = hn;
        op[ui*64 + b] = hn * p.Wo[u];
      }
      __syncthreads();
      if (t < 64){
        U64H4 h0;
        #pragma unroll
        for (int k = 0; k < 4; ++k) h0.h[k] = f2bf(hs[k*64 + t]);
        ast64(hbWu + t*256 + cb, h0.q);
        float po = op[t] + op[64 + t] + op[128 + t] + op[192 + t];
        astf(&p.out_part[t*256 + cb], po);
      }
      __syncthreads();                          // drain h/out_part stores
      if (t == 0) aadd32(&sync[(CC_L + ((bi - 320) & 15))*16], 1u);
    }
  }

  // ===== final out reduction =====
  if (bi == 960){
    if (t < 64){
      unsigned tgt = 16u * (unsigned)T_;
      for (;;){
        bool ok = (t < 16) ? (ald32(&sync[(CC_L + t)*16]) >= tgt) : true;
        if (__ballot(ok) == ~0ull) break;
        __builtin_amdgcn_s_sleep(1);
      }
      ast32(&sync[(RELC_L + t)*16], (unsigned)T_);
    }
    __syncthreads();
    out_reduce(p, 0, T_ - 1, smem, t, lane, w);
  } else if (bi > 960){
    wait1(&sync[(RELC_L + (bi & 63))*16], (unsigned)T_);
    out_reduce(p, bi - 960, T_ - 1, smem, t, lane, w);
  }
}

extern "C" void kernel_launch(void* const* d_in, const int* in_sizes, int n_in,
                              void* d_out, int out_size, void* d_ws, size_t ws_size,
                              hipStream_t stream){
  const float* inputs = (const float*)d_in[0];
  const float* We1 = (const float*)d_in[1];
  const float* be1 = (const float*)d_in[2];
  const float* We2 = (const float*)d_in[3];
  const float* be2 = (const float*)d_in[4];
  const float* W1  = (const float*)d_in[5];
  const float* b1  = (const float*)d_in[6];
  const float* W2  = (const float*)d_in[7];
  const float* b2  = (const float*)d_in[8];
  const float* V   = (const float*)d_in[9];
  // d_in[10] = bV: softmax shift-invariant, dropped
  const float* Wk  = (const float*)d_in[11];
  const float* Wr  = (const float*)d_in[12];
  const float* bl  = (const float*)d_in[13];
  const float* Wo  = (const float*)d_in[14];
  const float* bo  = (const float*)d_in[15];
  float* out = (float*)d_out;

  char* ws = (char*)d_ws;
  size_t off = 0;
  auto alloc = [&](size_t bytes) -> void* {
    void* pp = ws + off;
    off = (off + bytes + 255) & ~(size_t)255;
    return pp;
  };
  unsigned short* We1Tb = (unsigned short*)alloc((size_t)1024*128*2);
  unsigned short* We2Tb = (unsigned short*)alloc((size_t)1024*1024*2);
  unsigned short* W2Tb  = (unsigned short*)alloc((size_t)1024*1024*2);
  unsigned short* W1Tb  = (unsigned short*)alloc((size_t)1024*1024*2);
  unsigned short* WkTb  = (unsigned short*)alloc((size_t)4096*1024*2);
  unsigned short* WrTb  = (unsigned short*)alloc((size_t)4096*1024*2);
  unsigned short* h1tk  = (unsigned short*)alloc((size_t)BT_*U_*2);  // h1, then tk
  unsigned short* xv    = (unsigned short*)alloc((size_t)BT_*U_*2);
  float*          c     = (float*)alloc((size_t)B_*U_*4);
  unsigned short* hb0   = (unsigned short*)alloc((size_t)B_*U_*2);
  unsigned short* hb1   = (unsigned short*)alloc((size_t)B_*U_*2);
  unsigned short* ctxb  = (unsigned short*)alloc((size_t)B_*U_*2);
  float*          tq    = (float*)alloc((size_t)B_*U_*4);
  float*          ew    = (float*)alloc((size_t)B_*T_*4);
  float*          zh    = (float*)alloc((size_t)4*U_*64*4);
  float*          out_part = (float*)alloc((size_t)64*256*4);
  unsigned*       sync  = (unsigned*)alloc((size_t)SYNC_N*4);
  float*          vbound= (float*)alloc(256);
  if (ws_size < off) return;  // workspace too small: fail loudly

  init_kernel<<<256, 256, 0, stream>>>(c, hb0, hb1, sync, V, vbound);
  transpose_bf_kernel<<<(128/32)*(1024/32),  256, 0, stream>>>(We1, We1Tb, 128, 1024);
  transpose_bf_kernel<<<(1024/32)*(1024/32), 256, 0, stream>>>(We2, We2Tb, 1024, 1024);
  transpose_bf_kernel<<<(1024/32)*(1024/32), 256, 0, stream>>>(W2,  W2Tb,  1024, 1024);
  transpose_bf_kernel<<<(1024/32)*(1024/32), 256, 0, stream>>>(W1,  W1Tb,  1024, 1024);
  transpose_bf_kernel<<<(1024/32)*(4096/32), 256, 0, stream>>>(Wk,  WkTb,  1024, 4096);
  transpose_bf_kernel<<<(1024/32)*(4096/32), 256, 0, stream>>>(Wr,  WrTb,  1024, 4096);

  gemm_embed<1><<<4096, 256, 0, stream>>>((const void*)inputs, We1Tb, be1, h1tk, DIN_, 0);
  gemm_embed<0><<<4096, 256, 0, stream>>>((const void*)h1tk,   We2Tb, be2, xv,   U_,   0);
  gemm_embed<0><<<4096, 256, 0, stream>>>((const void*)xv,     W2Tb,  b2,  h1tk, U_,   1);

  SeqP sp;
  sp.W1Tb = W1Tb; sp.WkTb = WkTb; sp.WrTb = WrTb; sp.tk = h1tk; sp.xv = xv;
  sp.b1 = b1; sp.bl = bl; sp.V = V; sp.Wo = Wo; sp.bo = bo; sp.vbound = vbound;
  sp.tq = tq; sp.ew = ew; sp.c = c; sp.zh = zh;
  sp.out_part = out_part; sp.out = out;
  sp.ctxb = ctxb; sp.hb0 = hb0; sp.hb1 = hb1; sp.sync = sync;
  seq_kernel<<<dim3(G_), dim3(256), 0, stream>>>(sp);
}